// Round 8
// baseline (329.647 us; speedup 1.0000x reference)
//
#include <hip/hip_runtime.h>

// Problem constants
#define B_ 32
#define N_ 256
#define D_ 512
#define H_ 8
#define E_ 1024
#define HD_ 64

using u16 = unsigned short;
typedef short bf8_t __attribute__((ext_vector_type(8)));
typedef float f4_t __attribute__((ext_vector_type(4)));

__device__ __forceinline__ u16 f2bf(float f) {
  union { float f; unsigned u; } x; x.f = f;
  unsigned r = x.u + 0x7fffu + ((x.u >> 16) & 1u);
  return (u16)(r >> 16);
}
__device__ __forceinline__ float bf2f(u16 u) {
  union { unsigned u; float f; } x; x.u = ((unsigned)u) << 16; return x.f;
}
__device__ __forceinline__ f4_t mfma16(bf8_t a, bf8_t b, f4_t c) {
  return __builtin_amdgcn_mfma_f32_16x16x32_bf16(a, b, c, 0, 0, 0);
}
__device__ __forceinline__ void gload_lds16(const u16* g, u16* s) {
  __builtin_amdgcn_global_load_lds((const __attribute__((address_space(1))) void*)g,
                                   (__attribute__((address_space(3))) void*)s, 16, 0, 0);
}

// ---------------- all-weights f32 -> bf16 conversion (single launch) ----------------
__global__ __launch_bounds__(256) void cvt_all_kernel(
    const float* __restrict__ wq, const float* __restrict__ wk,
    const float* __restrict__ wv, const float* __restrict__ wo,
    const float* __restrict__ w1, const float* __restrict__ w2,
    u16* __restrict__ dq, u16* __restrict__ dk, u16* __restrict__ dv,
    u16* __restrict__ dox, u16* __restrict__ d1, u16* __restrict__ d2) {
  int blk = blockIdx.x;
  const float* src; u16* dst;
  if (blk < 256)        { src = wq; dst = dq; }
  else if (blk < 512)   { src = wk; dst = dk; blk -= 256; }
  else if (blk < 768)   { src = wv; dst = dv; blk -= 512; }
  else if (blk < 1024)  { src = wo; dst = dox; blk -= 768; }
  else if (blk < 2048)  { src = w1; dst = d1; blk -= 1024; }
  else                  { src = w2; dst = d2; blk -= 2048; }
  const int i = (blk * 256 + threadIdx.x) * 4;
  const float4 v = *(const float4*)(src + i);
  ushort4 o;
  o.x = f2bf(v.x); o.y = f2bf(v.y); o.z = f2bf(v.z); o.w = f2bf(v.w);
  *(ushort4*)(dst + i) = o;
}

// ---------------- LayerNorm (row of 512, f32 in -> bf16 out) ----------------
__global__ __launch_bounds__(256) void ln_kernel(const float* __restrict__ x,
                                                 const float* __restrict__ g,
                                                 const float* __restrict__ bta,
                                                 u16* __restrict__ out) {
  const int row = blockIdx.x, t = threadIdx.x;
  const float* xr = x + (size_t)row * D_;
  float v0 = xr[t], v1 = xr[t + 256];
  float s = v0 + v1, ss = v0 * v0 + v1 * v1;
  #pragma unroll
  for (int m = 1; m < 64; m <<= 1) { s += __shfl_xor(s, m, 64); ss += __shfl_xor(ss, m, 64); }
  __shared__ float red[8];
  const int wave = t >> 6, lane = t & 63;
  if (!lane) { red[wave] = s; red[wave + 4] = ss; }
  __syncthreads();
  s = red[0] + red[1] + red[2] + red[3];
  ss = red[4] + red[5] + red[6] + red[7];
  const float mean = s * (1.f / D_);
  const float var = ss * (1.f / D_) - mean * mean;
  const float rs = rsqrtf(var + 1e-5f);
  out[(size_t)row * D_ + t] = f2bf((v0 - mean) * rs * g[t] + bta[t]);
  out[(size_t)row * D_ + t + 256] = f2bf((v1 - mean) * rs * g[t + 256] + bta[t + 256]);
}

// ---------------- geo LN: rows of 64, f32 -> bf16 ----------------
__global__ __launch_bounds__(256) void geo_ln_kernel(const float* __restrict__ rgeo,
                                                     const float* __restrict__ g,
                                                     const float* __restrict__ b,
                                                     u16* __restrict__ gln) {
  const int wave = threadIdx.x >> 6, lane = threadIdx.x & 63;
  const int row = blockIdx.x * 4 + wave;
  const float gv = rgeo[(size_t)row * 64 + lane];
  float s = gv, ss = gv * gv;
  #pragma unroll
  for (int m = 1; m < 64; m <<= 1) { s += __shfl_xor(s, m, 64); ss += __shfl_xor(ss, m, 64); }
  const float mean = s * (1.f / 64.f);
  const float var = ss * (1.f / 64.f) - mean * mean;
  const float rs = rsqrtf(var + 1e-5f);
  gln[(size_t)row * 64 + lane] = f2bf((gv - mean) * rs * g[lane] + b[lane]);
}

// ---------------- edge bias GEMM: tb[b,h,e] = remb@Web^T + gln@Wgeo^T + biases ----------------
__global__ __launch_bounds__(256) void edge_gemm_kernel(
    const float* __restrict__ remb, const u16* __restrict__ gln,
    const float* __restrict__ Web, const float* __restrict__ beb,
    const float* __restrict__ Wgeo, const float* __restrict__ bgeo,
    float* __restrict__ tb) {
  __shared__ u16 sWeb[16 * 256];  // rows 8..15 zero
  __shared__ u16 sWgeo[16 * 64];
  const int t = threadIdx.x;
  for (int i = t; i < 2048; i += 256) { sWeb[i] = f2bf(Web[i]); sWeb[2048 + i] = 0; }
  for (int i = t; i < 512; i += 256)  { sWgeo[i] = f2bf(Wgeo[i]); sWgeo[512 + i] = 0; }
  __syncthreads();
  const int wave = t >> 6, lane = t & 63;
  const int am = lane & 15, quad = lane >> 4;
  const int e0 = blockIdx.x * 64 + wave * 16;

  f4_t acc = f4_t{0.f, 0.f, 0.f, 0.f};
  const float* ar = remb + (size_t)(e0 + am) * 256 + quad * 8;
  #pragma unroll
  for (int kt = 0; kt < 256; kt += 32) {
    const float4 p0 = *(const float4*)(ar + kt);
    const float4 p1 = *(const float4*)(ar + kt + 4);
    bf8_t a;
    a[0] = (short)f2bf(p0.x); a[1] = (short)f2bf(p0.y);
    a[2] = (short)f2bf(p0.z); a[3] = (short)f2bf(p0.w);
    a[4] = (short)f2bf(p1.x); a[5] = (short)f2bf(p1.y);
    a[6] = (short)f2bf(p1.z); a[7] = (short)f2bf(p1.w);
    const bf8_t bv = *(const bf8_t*)&sWeb[am * 256 + kt + quad * 8];
    acc = mfma16(a, bv, acc);
  }
  const u16* gr = gln + (size_t)(e0 + am) * 64 + quad * 8;
  #pragma unroll
  for (int kt = 0; kt < 64; kt += 32) {
    const bf8_t a2 = *(const bf8_t*)(gr + kt);
    const bf8_t bv2 = *(const bf8_t*)&sWgeo[am * 64 + kt + quad * 8];
    acc = mfma16(a2, bv2, acc);
  }
  if (am < 8) {
    const float bias_v = beb[am] + bgeo[am];
    #pragma unroll
    for (int r = 0; r < 4; ++r) {
      const int eg = e0 + quad * 4 + r;
      tb[(size_t)((eg >> 10) * H_ + am) * E_ + (eg & (E_ - 1))] = acc[r] + bias_v;
    }
  }
}

// ---------------- winner scatter (np last-write-wins emulation) ----------------
__global__ __launch_bounds__(256) void scatter_kernel(const int* __restrict__ edges,
                                                      const float* __restrict__ rmask,
                                                      int* __restrict__ win) {
  const int t = blockIdx.x * 256 + threadIdx.x;  // b*E + e
  if (t >= B_ * E_) return;
  if (rmask[t] == 0.f) return;
  const int b = t >> 10, e = t & (E_ - 1);
  int s = edges[2 * t], d = edges[2 * t + 1];
  s = min(max(s, 0), N_ - 1);
  d = min(max(d, 0), N_ - 1);
  int* wb = win + (size_t)b * N_ * N_;
  atomicMax(&wb[s * N_ + d], e);        // scatter pass 1: priority e
  atomicMax(&wb[d * N_ + s], E_ + e);   // scatter pass 2: priority E+e
}

// ---------------- fused attention (v4: M tile built with GLOBAL tb gathers) ----------------
// grid (N/64, H, B); block 256 (4 waves); wave handles 16 Q-rows.
// M build gathers bias values straight from global tb (4KB, L2-hot) -> no stb
// stage, no early barrier; M build and QK MFMAs are fully independent and
// overlap. Softmax inner loop = one sequential ds_read_u16 + fma per cell.
__global__ __launch_bounds__(256) void attn_kernel(
    const u16* __restrict__ q, const u16* __restrict__ k, const u16* __restrict__ vt,
    const float* __restrict__ tb, const int* __restrict__ win,
    const float* __restrict__ nm, u16* __restrict__ out) {
  __shared__ u16 sM[64 * 264];    // 33792 B; reused as Ps
  const int t = threadIdx.x;
  const int wave = t >> 6, lane = t & 63;
  const int am = lane & 15, quad = lane >> 4;
  const int qt = blockIdx.x, h = blockIdx.y, b = blockIdx.z;
  const int bh = b * H_ + h;
  const int q0 = qt * 64;

  // ---- M tile build: decode win + gather tb from global + fold all masks -> bf16
  {
    const int4* wsrc = (const int4*)(win + ((size_t)b * N_ + q0) * N_);
    const float* nmb = nm + b * N_;
    const float* tbb = tb + (size_t)bh * E_;
    const int col0 = (t & 63) * 4;                    // loop-invariant per thread
    const float4 nm4 = *(const float4*)(nmb + col0);  // hoisted (was reloaded 16x in v3)
    const float nmc[4] = {nm4.x, nm4.y, nm4.z, nm4.w};
    #pragma unroll
    for (int kk = 0; kk < 16; ++kk) {
      const int rowl = kk * 4 + wave;                 // local row 0..63
      const int4 w4 = wsrc[rowl * 64 + (t & 63)];
      const float nmrv = nmb[q0 + rowl];
      const int wv[4] = {w4.x, w4.y, w4.z, w4.w};
      float vals[4];
      #pragma unroll
      for (int c = 0; c < 4; ++c) {
        const int w = wv[c];
        const bool has = w >= 0;
        const float tv = tbb[w & 1023];   // L2-hot 4KB; safe for w<0 (discarded)
        const bool ok = (nmrv != 0.f) && (nmc[c] != 0.f) &&
                        ((q0 + rowl) == (col0 + c) || has);
        vals[c] = ok ? (has ? tv : 0.f) : -3.0e38f;
      }
      ushort4 o;
      o.x = f2bf(vals[0]); o.y = f2bf(vals[1]);
      o.z = f2bf(vals[2]); o.w = f2bf(vals[3]);
      *(ushort4*)&sM[rowl * 264 + col0] = o;
    }
  }

  // ---- QK^T (independent of M build; overlaps on MFMA pipe)
  f4_t sacc[16];
  #pragma unroll
  for (int j = 0; j < 16; ++j) sacc[j] = f4_t{0.f, 0.f, 0.f, 0.f};
  const u16* qbase = q + ((size_t)bh * N_ + q0 + wave * 16) * HD_;
  const bf8_t aq0 = *(const bf8_t*)&qbase[am * HD_ + quad * 8];
  const bf8_t aq1 = *(const bf8_t*)&qbase[am * HD_ + 32 + quad * 8];
  const u16* kbase = k + (size_t)bh * N_ * HD_;
  #pragma unroll
  for (int j = 0; j < 16; ++j) {
    const u16* kp = kbase + (size_t)(j * 16 + am) * HD_ + quad * 8;
    sacc[j] = mfma16(aq0, *(const bf8_t*)kp, sacc[j]);
    sacc[j] = mfma16(aq1, *(const bf8_t*)(kp + 32), sacc[j]);
  }
  __syncthreads();  // M tile complete

  // ---- softmax: s = qk*0.125 + M (all masking pre-folded)
  int lrow[4]; float rmax[4], rsum[4];
  #pragma unroll
  for (int r = 0; r < 4; ++r) {
    lrow[r] = wave * 16 + quad * 4 + r;
    rmax[r] = -3.402823466e38f;
    rsum[r] = 0.f;
  }
  #pragma unroll
  for (int j = 0; j < 16; ++j) {
    #pragma unroll
    for (int r = 0; r < 4; ++r) {
      const float m = bf2f(sM[lrow[r] * 264 + j * 16 + am]);
      const float s = fmaf(sacc[j][r], 0.125f, m);
      sacc[j][r] = s;
      rmax[r] = fmaxf(rmax[r], s);
    }
  }
  #pragma unroll
  for (int m = 1; m < 16; m <<= 1)
    #pragma unroll
    for (int r = 0; r < 4; ++r) rmax[r] = fmaxf(rmax[r], __shfl_xor(rmax[r], m, 64));
  #pragma unroll
  for (int j = 0; j < 16; ++j)
    #pragma unroll
    for (int r = 0; r < 4; ++r) {
      const float e = __expf(sacc[j][r] - rmax[r]);
      sacc[j][r] = e;
      rsum[r] += e;
    }
  #pragma unroll
  for (int m = 1; m < 16; m <<= 1)
    #pragma unroll
    for (int r = 0; r < 4; ++r) rsum[r] += __shfl_xor(rsum[r], m, 64);
  float rinv[4];
  #pragma unroll
  for (int r = 0; r < 4; ++r) rinv[r] = 1.f / rsum[r];

  __syncthreads();  // all waves done reading sM before Ps overwrite
  u16* ps = sM + wave * 16 * 264;
  #pragma unroll
  for (int j = 0; j < 16; ++j)
    #pragma unroll
    for (int r = 0; r < 4; ++r)
      ps[(quad * 4 + r) * 264 + j * 16 + am] = f2bf(sacc[j][r] * rinv[r]);
  __syncthreads();

  f4_t oacc[4];
  #pragma unroll
  for (int t2 = 0; t2 < 4; ++t2) oacc[t2] = f4_t{0.f, 0.f, 0.f, 0.f};
  const u16* vb = vt + (size_t)bh * HD_ * N_;
  #pragma unroll
  for (int kc = 0; kc < 8; ++kc) {
    const bf8_t ap = *(const bf8_t*)&ps[am * 264 + kc * 32 + quad * 8];
    #pragma unroll
    for (int t2 = 0; t2 < 4; ++t2) {
      const u16* vp = vb + (size_t)(t2 * 16 + am) * N_ + kc * 32 + quad * 8;
      oacc[t2] = mfma16(ap, *(const bf8_t*)vp, oacc[t2]);
    }
  }
  #pragma unroll
  for (int t2 = 0; t2 < 4; ++t2)
    #pragma unroll
    for (int r = 0; r < 4; ++r) {
      const int n = q0 + wave * 16 + quad * 4 + r;
      const int d = t2 * 16 + am;
      out[((size_t)(b * N_ + n)) * D_ + h * HD_ + d] = f2bf(oacc[t2][r]);
    }
}

// ---------------- GEMM: C = A @ W^T (+epilogue), global_load_lds staging ----------------
template <int MODE, int BN>
__global__ __launch_bounds__(256, 2) void gemm_k(
    const u16* __restrict__ A,
    const u16* __restrict__ W0, const u16* __restrict__ W1, const u16* __restrict__ W2,
    const float* __restrict__ b0, const float* __restrict__ b1, const float* __restrict__ b2,
    void* d0, void* d1, void* d2,
    const void* res, const float* __restrict__ nmask, int K) {
  constexpr int MJ = BN / 32;
  constexpr int CB = BN / 32;
  __shared__ u16 As[128 * 64];
  __shared__ u16 Bs[BN * 64];
  const int tid = threadIdx.x;
  const int wave = tid >> 6, lane = tid & 63;
  const int am = lane & 15, quad = lane >> 4;
  const int m0 = blockIdx.x * 128;
  int n0, proj = 0;
  const u16* W;
  const float* bias;
  if constexpr (MODE == 0) {
    proj = blockIdx.y >> 2;
    n0 = (blockIdx.y & 3) * BN;
    W = proj == 0 ? W0 : (proj == 1 ? W1 : W2);
    bias = proj == 0 ? b0 : (proj == 1 ? b1 : b2);
  } else {
    n0 = blockIdx.y * BN;
    W = W0;
    bias = b0;
  }
  const int wm = (wave >> 1) * 64;
  const int wn = (wave & 1) * (BN / 2);

  f4_t acc[4][MJ];
  #pragma unroll
  for (int i = 0; i < 4; ++i)
    #pragma unroll
    for (int j = 0; j < MJ; ++j) acc[i][j] = f4_t{0.f, 0.f, 0.f, 0.f};

  int arow[4], aq[4], brow[CB], bq[CB];
  #pragma unroll
  for (int c = 0; c < 4; ++c) {
    const int g = (wave * 4 + c) * 64 + lane;
    arow[c] = g >> 3;
    aq[c] = (g & 7) ^ (arow[c] & 7);
  }
  #pragma unroll
  for (int c = 0; c < CB; ++c) {
    const int g = (wave * CB + c) * 64 + lane;
    brow[c] = g >> 3;
    bq[c] = (g & 7) ^ (brow[c] & 7);
  }

  for (int kt = 0; kt < K; kt += 64) {
    #pragma unroll
    for (int c = 0; c < 4; ++c)
      gload_lds16(A + (size_t)(m0 + arow[c]) * K + kt + aq[c] * 8, &As[(wave * 4 + c) * 512]);
    #pragma unroll
    for (int c = 0; c < CB; ++c)
      gload_lds16(W + (size_t)(n0 + brow[c]) * K + kt + bq[c] * 8, &Bs[(wave * CB + c) * 512]);
    __syncthreads();
    #pragma unroll
    for (int kc = 0; kc < 2; ++kc) {
      bf8_t af[4], bfv[MJ];
      #pragma unroll
      for (int i = 0; i < 4; ++i) {
        const int r = wm + i * 16 + am;
        af[i] = *(const bf8_t*)&As[r * 64 + (((kc * 4 + quad) ^ (r & 7)) * 8)];
      }
      #pragma unroll
      for (int j = 0; j < MJ; ++j) {
        const int r = wn + j * 16 + am;
        bfv[j] = *(const bf8_t*)&Bs[r * 64 + (((kc * 4 + quad) ^ (r & 7)) * 8)];
      }
      #pragma unroll
      for (int i = 0; i < 4; ++i)
        #pragma unroll
        for (int j = 0; j < MJ; ++j) acc[i][j] = mfma16(af[i], bfv[j], acc[i][j]);
    }
    __syncthreads();
  }

  const int cb = n0 + wn + am;
  const int rb = m0 + wm + quad * 4;
  #pragma unroll
  for (int j = 0; j < MJ; ++j) {
    const int col = cb + j * 16;
    const float bv = bias[col];
    #pragma unroll
    for (int i = 0; i < 4; ++i) {
      #pragma unroll
      for (int r = 0; r < 4; ++r) {
        const int row = rb + i * 16 + r;
        float v = acc[i][j][r] + bv;
        if constexpr (MODE == 0) {
          const int b = row >> 8, n = row & (N_ - 1);
          const int h = col >> 6, hd = col & (HD_ - 1);
          u16* dst = (u16*)(proj == 0 ? d0 : (proj == 1 ? d1 : d2));
          const size_t idx = (proj < 2) ? (((size_t)(b * H_ + h) * N_ + n) * HD_ + hd)
                                        : (((size_t)(b * H_ + h) * HD_ + hd) * N_ + n);
          dst[idx] = f2bf(v);
        } else if constexpr (MODE == 2) {
          v += ((const float*)res)[(size_t)row * D_ + col];
          ((float*)d0)[(size_t)row * D_ + col] = v;
        } else if constexpr (MODE == 3) {
          v = v / (1.f + __expf(-v));
          ((u16*)d0)[(size_t)row * 2048 + col] = f2bf(v);
        } else {
          v += ((const float*)res)[(size_t)row * D_ + col];
          v *= nmask[row];
          ((float*)d0)[(size_t)row * D_ + col] = v;
        }
      }
    }
  }
}

extern "C" void kernel_launch(void* const* d_in, const int* in_sizes, int n_in,
                              void* d_out, int out_size, void* d_ws, size_t ws_size,
                              hipStream_t stream) {
  const float* x     = (const float*)d_in[0];
  const float* nm    = (const float*)d_in[1];
  const int*   edges = (const int*)d_in[2];
  const float* rmask = (const float*)d_in[3];
  const float* remb  = (const float*)d_in[4];
  const float* rgeo  = (const float*)d_in[5];
  const float* Wq = (const float*)d_in[6];  const float* bq = (const float*)d_in[7];
  const float* Wk = (const float*)d_in[8];  const float* bk = (const float*)d_in[9];
  const float* Wv = (const float*)d_in[10]; const float* bv = (const float*)d_in[11];
  const float* Web = (const float*)d_in[12]; const float* beb = (const float*)d_in[13];
  const float* glng = (const float*)d_in[14]; const float* glnb = (const float*)d_in[15];
  const float* Wgeo = (const float*)d_in[16]; const float* bgeo = (const float*)d_in[17];
  const float* Wout = (const float*)d_in[18]; const float* bout = (const float*)d_in[19];
  const float* ng = (const float*)d_in[20]; const float* nb = (const float*)d_in[21];
  const float* fg = (const float*)d_in[22]; const float* fb = (const float*)d_in[23];
  const float* Wff1 = (const float*)d_in[24]; const float* bff1 = (const float*)d_in[25];
  const float* Wff2 = (const float*)d_in[26]; const float* bff2 = (const float*)d_in[27];

  char* ws = (char*)d_ws;
  // Workspace (peak 49,283,072 B — same as rounds 4-7):
  u16*   xn      = (u16*)(ws + 0);
  u16*   qb      = (u16*)(ws + 8388608);
  u16*   kb      = (u16*)(ws + 16777216);
  u16*   vtb     = (u16*)(ws + 25165824);
  u16*   h1      = (u16*)(ws + 0);          // overlays dead xn/qb/kb/vtb in FF
  u16*   gln     = (u16*)(ws + 0);          // overlays xn (dead between QKV and attn)
  int*   win     = (int*)(ws + 33554432);
  u16*   x2n     = (u16*)(ws + 33554432);   // overlays dead win
  float* tb      = (float*)(ws + 41943040);
  u16* Wq16   = (u16*)(ws + 42991616);
  u16* Wk16   = (u16*)(ws + 43515904);
  u16* Wv16   = (u16*)(ws + 44040192);
  u16* Wout16 = (u16*)(ws + 44564480);
  u16* Wff116 = (u16*)(ws + 45088768);
  u16* Wff216 = (u16*)(ws + 47185920);
  u16*   attnout = xn;
  float* out     = (float*)d_out;

  // 0. weight conversion f32 -> bf16 (one launch) ; win init via async memset
  cvt_all_kernel<<<3072, 256, 0, stream>>>(Wq, Wk, Wv, Wout, Wff1, Wff2,
                                           Wq16, Wk16, Wv16, Wout16, Wff116, Wff216);
  hipMemsetAsync(win, 0xFF, (size_t)B_ * N_ * N_ * sizeof(int), stream);

  // 1. xn = LN(x)
  ln_kernel<<<B_ * N_, 256, 0, stream>>>(x, ng, nb, xn);
  // 2. fused QKV projections (q,k: (b,h,n,hd) ; v: transposed (b,h,hd,n))
  gemm_k<0, 128><<<dim3(64, 12), 256, 0, stream>>>(xn, Wq16, Wk16, Wv16, bq, bk, bv,
                                                   (void*)qb, (void*)kb, (void*)vtb,
                                                   nullptr, nullptr, D_);
  // 3. winner scatter + edge bias (MFMA path; gln overlays dead xn)
  scatter_kernel<<<(B_ * E_ + 255) / 256, 256, 0, stream>>>(edges, rmask, win);
  geo_ln_kernel<<<B_ * E_ / 4, 256, 0, stream>>>(rgeo, glng, glnb, gln);
  edge_gemm_kernel<<<B_ * E_ / 64, 256, 0, stream>>>(remb, gln, Web, beb, Wgeo, bgeo, tb);
  // 4. attention -> attnout (bf16)
  attn_kernel<<<dim3(N_ / 64, H_, B_), 256, 0, stream>>>(qb, kb, vtb, tb, win, nm, attnout);
  // 5. x2 = x + attnout @ Wout^T + bout  -> d_out (f32); BN=64 -> 512 blocks
  gemm_k<2, 64><<<dim3(64, 8), 256, 0, stream>>>(attnout, Wout16, nullptr, nullptr,
                                                 bout, nullptr, nullptr,
                                                 (void*)out, nullptr, nullptr,
                                                 (const void*)x, nullptr, D_);
  // 6. x2n = LN(x2)
  ln_kernel<<<B_ * N_, 256, 0, stream>>>(out, fg, fb, x2n);
  // 7. h1 = silu(x2n @ Wff1^T + bff1)
  gemm_k<3, 128><<<dim3(64, 16), 256, 0, stream>>>(x2n, Wff116, nullptr, nullptr,
                                                   bff1, nullptr, nullptr,
                                                   (void*)h1, nullptr, nullptr, nullptr, nullptr, D_);
  // 8. out = (x2 + h1 @ Wff2^T + bff2) * node_mask
  gemm_k<4, 64><<<dim3(64, 8), 256, 0, stream>>>(h1, Wff216, nullptr, nullptr,
                                                 bff2, nullptr, nullptr,
                                                 (void*)out, nullptr, nullptr,
                                                 (const void*)out, nm, 2048);
}

// Round 9
// 318.839 us; speedup vs baseline: 1.0339x; 1.0339x over previous
//
#include <hip/hip_runtime.h>

// Problem constants
#define B_ 32
#define N_ 256
#define D_ 512
#define H_ 8
#define E_ 1024
#define HD_ 64

using u16 = unsigned short;
typedef short bf8_t __attribute__((ext_vector_type(8)));
typedef float f4_t __attribute__((ext_vector_type(4)));

__device__ __forceinline__ u16 f2bf(float f) {
  union { float f; unsigned u; } x; x.f = f;
  unsigned r = x.u + 0x7fffu + ((x.u >> 16) & 1u);
  return (u16)(r >> 16);
}
__device__ __forceinline__ f4_t mfma16(bf8_t a, bf8_t b, f4_t c) {
  return __builtin_amdgcn_mfma_f32_16x16x32_bf16(a, b, c, 0, 0, 0);
}
__device__ __forceinline__ void gload_lds16(const u16* g, u16* s) {
  __builtin_amdgcn_global_load_lds((const __attribute__((address_space(1))) void*)g,
                                   (__attribute__((address_space(3))) void*)s, 16, 0, 0);
}

// ---------------- prep: cvt + ln1 + scatter + edge_gemm(inline geo-LN), one launch --------
// block ranges: [0,3072) weight cvt; [3072,11264) LN(x); [11264,11392) scatter;
//               [11392,11904) edge-bias GEMM with inlined geo LayerNorm.
// All four segments are mutually independent (edge reads only raw inputs).
__global__ __launch_bounds__(256) void prep_kernel(
    // cvt
    const float* __restrict__ wq, const float* __restrict__ wk,
    const float* __restrict__ wv, const float* __restrict__ wo,
    const float* __restrict__ w1, const float* __restrict__ w2,
    u16* __restrict__ dq, u16* __restrict__ dk, u16* __restrict__ dv,
    u16* __restrict__ dox, u16* __restrict__ d1, u16* __restrict__ d2,
    // ln1
    const float* __restrict__ x, const float* __restrict__ ng,
    const float* __restrict__ nb, u16* __restrict__ xn,
    // scatter
    const int* __restrict__ edges, const float* __restrict__ rmask,
    int* __restrict__ win,
    // edge
    const float* __restrict__ remb, const float* __restrict__ rgeo,
    const float* __restrict__ Web, const float* __restrict__ beb,
    const float* __restrict__ glng, const float* __restrict__ glnb,
    const float* __restrict__ Wgeo, const float* __restrict__ bgeo,
    float* __restrict__ tb) {
  __shared__ float red[8];
  __shared__ u16 sWeb[16 * 256];
  __shared__ u16 sWgeo[16 * 64];
  __shared__ float sLgb[128];
  const int t = threadIdx.x;
  const int blk0 = blockIdx.x;

  if (blk0 < 3072) {
    // ---- weight f32 -> bf16 ----
    int blk = blk0;
    const float* src; u16* dst;
    if (blk < 256)        { src = wq; dst = dq; }
    else if (blk < 512)   { src = wk; dst = dk; blk -= 256; }
    else if (blk < 768)   { src = wv; dst = dv; blk -= 512; }
    else if (blk < 1024)  { src = wo; dst = dox; blk -= 768; }
    else if (blk < 2048)  { src = w1; dst = d1; blk -= 1024; }
    else                  { src = w2; dst = d2; blk -= 2048; }
    const int i = (blk * 256 + t) * 4;
    const float4 v = *(const float4*)(src + i);
    ushort4 o;
    o.x = f2bf(v.x); o.y = f2bf(v.y); o.z = f2bf(v.z); o.w = f2bf(v.w);
    *(ushort4*)(dst + i) = o;
  } else if (blk0 < 11264) {
    // ---- LN(x) row of 512, f32 -> bf16 ----
    const int row = blk0 - 3072;
    const float* xr = x + (size_t)row * D_;
    float v0 = xr[t], v1 = xr[t + 256];
    float s = v0 + v1, ss = v0 * v0 + v1 * v1;
    #pragma unroll
    for (int m = 1; m < 64; m <<= 1) { s += __shfl_xor(s, m, 64); ss += __shfl_xor(ss, m, 64); }
    const int wave = t >> 6, lane = t & 63;
    if (!lane) { red[wave] = s; red[wave + 4] = ss; }
    __syncthreads();
    s = red[0] + red[1] + red[2] + red[3];
    ss = red[4] + red[5] + red[6] + red[7];
    const float mean = s * (1.f / D_);
    const float var = ss * (1.f / D_) - mean * mean;
    const float rs = rsqrtf(var + 1e-5f);
    xn[(size_t)row * D_ + t] = f2bf((v0 - mean) * rs * ng[t] + nb[t]);
    xn[(size_t)row * D_ + t + 256] = f2bf((v1 - mean) * rs * ng[t + 256] + nb[t + 256]);
  } else if (blk0 < 11392) {
    // ---- winner scatter (np last-write-wins) ----
    const int idx = (blk0 - 11264) * 256 + t;  // b*E + e
    if (rmask[idx] != 0.f) {
      const int b = idx >> 10, e = idx & (E_ - 1);
      int s = edges[2 * idx], d = edges[2 * idx + 1];
      s = min(max(s, 0), N_ - 1);
      d = min(max(d, 0), N_ - 1);
      int* wb = win + (size_t)b * N_ * N_;
      atomicMax(&wb[s * N_ + d], e);        // pass 1: priority e
      atomicMax(&wb[d * N_ + s], E_ + e);   // pass 2: priority E+e
    }
  } else {
    // ---- edge bias GEMM with inline geo LN ----
    const int eblk = blk0 - 11392;
    for (int i = t; i < 2048; i += 256) { sWeb[i] = f2bf(Web[i]); sWeb[2048 + i] = 0; }
    for (int i = t; i < 512; i += 256)  { sWgeo[i] = f2bf(Wgeo[i]); sWgeo[512 + i] = 0; }
    if (t < 64) { sLgb[t] = glng[t]; sLgb[64 + t] = glnb[t]; }
    __syncthreads();
    const int wave = t >> 6, lane = t & 63;
    const int am = lane & 15, quad = lane >> 4;
    const int e0 = eblk * 64 + wave * 16;

    f4_t acc = f4_t{0.f, 0.f, 0.f, 0.f};
    const float* ar = remb + (size_t)(e0 + am) * 256 + quad * 8;
    #pragma unroll
    for (int kt = 0; kt < 256; kt += 32) {
      const float4 p0 = *(const float4*)(ar + kt);
      const float4 p1 = *(const float4*)(ar + kt + 4);
      bf8_t a;
      a[0] = (short)f2bf(p0.x); a[1] = (short)f2bf(p0.y);
      a[2] = (short)f2bf(p0.z); a[3] = (short)f2bf(p0.w);
      a[4] = (short)f2bf(p1.x); a[5] = (short)f2bf(p1.y);
      a[6] = (short)f2bf(p1.z); a[7] = (short)f2bf(p1.w);
      const bf8_t bv = *(const bf8_t*)&sWeb[am * 256 + kt + quad * 8];
      acc = mfma16(a, bv, acc);
    }
    // geo: row (e0+am), lane holds elems quad*8..+7 and 32+quad*8..+7
    const float* gr = rgeo + (size_t)(e0 + am) * 64;
    float v[16];
    {
      const float4 p0 = *(const float4*)(gr + quad * 8);
      const float4 p1 = *(const float4*)(gr + quad * 8 + 4);
      const float4 p2 = *(const float4*)(gr + 32 + quad * 8);
      const float4 p3 = *(const float4*)(gr + 32 + quad * 8 + 4);
      v[0] = p0.x; v[1] = p0.y; v[2] = p0.z; v[3] = p0.w;
      v[4] = p1.x; v[5] = p1.y; v[6] = p1.z; v[7] = p1.w;
      v[8] = p2.x; v[9] = p2.y; v[10] = p2.z; v[11] = p2.w;
      v[12] = p3.x; v[13] = p3.y; v[14] = p3.z; v[15] = p3.w;
    }
    float s = 0.f, ss = 0.f;
    #pragma unroll
    for (int j = 0; j < 16; ++j) { s += v[j]; ss += v[j] * v[j]; }
    s += __shfl_xor(s, 16, 64);  ss += __shfl_xor(ss, 16, 64);
    s += __shfl_xor(s, 32, 64);  ss += __shfl_xor(ss, 32, 64);
    const float mean = s * (1.f / 64.f);
    const float rs = rsqrtf(ss * (1.f / 64.f) - mean * mean + 1e-5f);
    bf8_t a2, a3;
    #pragma unroll
    for (int j = 0; j < 8; ++j) {
      a2[j] = (short)f2bf((v[j] - mean) * rs * sLgb[quad * 8 + j] + sLgb[64 + quad * 8 + j]);
      a3[j] = (short)f2bf((v[8 + j] - mean) * rs * sLgb[32 + quad * 8 + j] +
                          sLgb[96 + quad * 8 + j]);
    }
    acc = mfma16(a2, *(const bf8_t*)&sWgeo[am * 64 + quad * 8], acc);
    acc = mfma16(a3, *(const bf8_t*)&sWgeo[am * 64 + 32 + quad * 8], acc);
    if (am < 8) {
      const float bias_v = beb[am] + bgeo[am];
      #pragma unroll
      for (int r = 0; r < 4; ++r) {
        const int eg = e0 + quad * 4 + r;
        tb[(size_t)((eg >> 10) * H_ + am) * E_ + (eg & (E_ - 1))] = acc[r] + bias_v;
      }
    }
  }
}

// ---------------- LayerNorm (row of 512, f32 in -> bf16 out) ----------------
__global__ __launch_bounds__(256) void ln_kernel(const float* __restrict__ x,
                                                 const float* __restrict__ g,
                                                 const float* __restrict__ bta,
                                                 u16* __restrict__ out) {
  const int row = blockIdx.x, t = threadIdx.x;
  const float* xr = x + (size_t)row * D_;
  float v0 = xr[t], v1 = xr[t + 256];
  float s = v0 + v1, ss = v0 * v0 + v1 * v1;
  #pragma unroll
  for (int m = 1; m < 64; m <<= 1) { s += __shfl_xor(s, m, 64); ss += __shfl_xor(ss, m, 64); }
  __shared__ float red[8];
  const int wave = t >> 6, lane = t & 63;
  if (!lane) { red[wave] = s; red[wave + 4] = ss; }
  __syncthreads();
  s = red[0] + red[1] + red[2] + red[3];
  ss = red[4] + red[5] + red[6] + red[7];
  const float mean = s * (1.f / D_);
  const float var = ss * (1.f / D_) - mean * mean;
  const float rs = rsqrtf(var + 1e-5f);
  out[(size_t)row * D_ + t] = f2bf((v0 - mean) * rs * g[t] + bta[t]);
  out[(size_t)row * D_ + t + 256] = f2bf((v1 - mean) * rs * g[t + 256] + bta[t + 256]);
}

// ---------------- fused attention (r6 v2: LDS-staged win + tb) ----------------
// grid (N/64, H, B); block 256 (4 waves); wave handles 16 Q-rows
__global__ __launch_bounds__(256) void attn_kernel(
    const u16* __restrict__ q, const u16* __restrict__ k, const u16* __restrict__ vt,
    const float* __restrict__ tb, const int* __restrict__ win,
    const float* __restrict__ nm, u16* __restrict__ out) {
  __shared__ u16 swin[64 * 268];  // 34304 B; reused as Ps
  __shared__ float stb[E_];       // 4 KB
  const int t = threadIdx.x;
  const int wave = t >> 6, lane = t & 63;
  const int am = lane & 15, quad = lane >> 4;
  const int qt = blockIdx.x, h = blockIdx.y, b = blockIdx.z;
  const int bh = b * H_ + h;
  const int q0 = qt * 64;

  ((float4*)stb)[t] = ((const float4*)(tb + (size_t)bh * E_))[t];
  {
    const int4* wsrc = (const int4*)(win + ((size_t)b * N_ + q0) * N_);
    #pragma unroll
    for (int kk = 0; kk < 16; ++kk) {
      const int g = kk * 256 + t;
      const int4 w4 = wsrc[g];
      ushort4 o;
      o.x = (u16)w4.x; o.y = (u16)w4.y; o.z = (u16)w4.z; o.w = (u16)w4.w;
      *(ushort4*)&swin[(g >> 6) * 268 + (g & 63) * 4] = o;
    }
  }

  f4_t sacc[16];
  #pragma unroll
  for (int j = 0; j < 16; ++j) sacc[j] = f4_t{0.f, 0.f, 0.f, 0.f};
  const u16* qbase = q + ((size_t)bh * N_ + q0 + wave * 16) * HD_;
  const bf8_t aq0 = *(const bf8_t*)&qbase[am * HD_ + quad * 8];
  const bf8_t aq1 = *(const bf8_t*)&qbase[am * HD_ + 32 + quad * 8];
  const u16* kbase = k + (size_t)bh * N_ * HD_;
  #pragma unroll
  for (int j = 0; j < 16; ++j) {
    const u16* kp = kbase + (size_t)(j * 16 + am) * HD_ + quad * 8;
    sacc[j] = mfma16(aq0, *(const bf8_t*)kp, sacc[j]);
    sacc[j] = mfma16(aq1, *(const bf8_t*)(kp + 32), sacc[j]);
  }
  __syncthreads();  // staging complete

  int lrow[4]; float nmr[4], rmax[4], rsum[4];
  #pragma unroll
  for (int r = 0; r < 4; ++r) {
    lrow[r] = wave * 16 + quad * 4 + r;
    nmr[r] = nm[b * N_ + q0 + lrow[r]];
    rmax[r] = -3.402823466e38f;
    rsum[r] = 0.f;
  }
  #pragma unroll
  for (int j = 0; j < 16; ++j) {
    const int cg = j * 16 + am;
    const float nmc = nm[b * N_ + cg];
    #pragma unroll
    for (int r = 0; r < 4; ++r) {
      const u16 w16 = swin[lrow[r] * 268 + cg];
      const bool has = (w16 != 0xFFFFu);
      const int idx = has ? ((w16 >= 1024) ? (w16 - 1024) : (int)w16) : 0;
      float s = sacc[j][r] * 0.125f;
      s += has ? stb[idx] : 0.f;
      const bool ok = (nmr[r] != 0.f) && (nmc != 0.f) && ((q0 + lrow[r]) == cg || has);
      s = ok ? s : -3.402823466e38f;
      sacc[j][r] = s;
      rmax[r] = fmaxf(rmax[r], s);
    }
  }
  #pragma unroll
  for (int m = 1; m < 16; m <<= 1)
    #pragma unroll
    for (int r = 0; r < 4; ++r) rmax[r] = fmaxf(rmax[r], __shfl_xor(rmax[r], m, 64));
  #pragma unroll
  for (int j = 0; j < 16; ++j)
    #pragma unroll
    for (int r = 0; r < 4; ++r) {
      const float e = __expf(sacc[j][r] - rmax[r]);
      sacc[j][r] = e;
      rsum[r] += e;
    }
  #pragma unroll
  for (int m = 1; m < 16; m <<= 1)
    #pragma unroll
    for (int r = 0; r < 4; ++r) rsum[r] += __shfl_xor(rsum[r], m, 64);
  float rinv[4];
  #pragma unroll
  for (int r = 0; r < 4; ++r) rinv[r] = 1.f / rsum[r];

  __syncthreads();  // all waves done reading swin before Ps overwrite
  u16* ps = swin + wave * 16 * 264;
  #pragma unroll
  for (int j = 0; j < 16; ++j)
    #pragma unroll
    for (int r = 0; r < 4; ++r)
      ps[(quad * 4 + r) * 264 + j * 16 + am] = f2bf(sacc[j][r] * rinv[r]);
  __syncthreads();

  f4_t oacc[4];
  #pragma unroll
  for (int t2 = 0; t2 < 4; ++t2) oacc[t2] = f4_t{0.f, 0.f, 0.f, 0.f};
  const u16* vb = vt + (size_t)bh * HD_ * N_;
  #pragma unroll
  for (int kc = 0; kc < 8; ++kc) {
    const bf8_t ap = *(const bf8_t*)&ps[am * 264 + kc * 32 + quad * 8];
    #pragma unroll
    for (int t2 = 0; t2 < 4; ++t2) {
      const u16* vp = vb + (size_t)(t2 * 16 + am) * N_ + kc * 32 + quad * 8;
      oacc[t2] = mfma16(ap, *(const bf8_t*)vp, oacc[t2]);
    }
  }
  #pragma unroll
  for (int t2 = 0; t2 < 4; ++t2)
    #pragma unroll
    for (int r = 0; r < 4; ++r) {
      const int n = q0 + wave * 16 + quad * 4 + r;
      const int d = t2 * 16 + am;
      out[((size_t)(b * N_ + n)) * D_ + h * HD_ + d] = f2bf(oacc[t2][r]);
    }
}

// ---------------- GEMM: C = A @ W^T (+epilogue), global_load_lds staging ----------------
template <int MODE, int BN>
__global__ __launch_bounds__(256, 2) void gemm_k(
    const u16* __restrict__ A,
    const u16* __restrict__ W0, const u16* __restrict__ W1, const u16* __restrict__ W2,
    const float* __restrict__ b0, const float* __restrict__ b1, const float* __restrict__ b2,
    void* d0, void* d1, void* d2,
    const void* res, const float* __restrict__ nmask, int K) {
  constexpr int MJ = BN / 32;
  constexpr int CB = BN / 32;
  __shared__ u16 As[128 * 64];
  __shared__ u16 Bs[BN * 64];
  const int tid = threadIdx.x;
  const int wave = tid >> 6, lane = tid & 63;
  const int am = lane & 15, quad = lane >> 4;
  const int m0 = blockIdx.x * 128;
  int n0, proj = 0;
  const u16* W;
  const float* bias;
  if constexpr (MODE == 0) {
    proj = blockIdx.y >> 2;
    n0 = (blockIdx.y & 3) * BN;
    W = proj == 0 ? W0 : (proj == 1 ? W1 : W2);
    bias = proj == 0 ? b0 : (proj == 1 ? b1 : b2);
  } else {
    n0 = blockIdx.y * BN;
    W = W0;
    bias = b0;
  }
  const int wm = (wave >> 1) * 64;
  const int wn = (wave & 1) * (BN / 2);

  f4_t acc[4][MJ];
  #pragma unroll
  for (int i = 0; i < 4; ++i)
    #pragma unroll
    for (int j = 0; j < MJ; ++j) acc[i][j] = f4_t{0.f, 0.f, 0.f, 0.f};

  int arow[4], aq[4], brow[CB], bq[CB];
  #pragma unroll
  for (int c = 0; c < 4; ++c) {
    const int g = (wave * 4 + c) * 64 + lane;
    arow[c] = g >> 3;
    aq[c] = (g & 7) ^ (arow[c] & 7);
  }
  #pragma unroll
  for (int c = 0; c < CB; ++c) {
    const int g = (wave * CB + c) * 64 + lane;
    brow[c] = g >> 3;
    bq[c] = (g & 7) ^ (brow[c] & 7);
  }

  for (int kt = 0; kt < K; kt += 64) {
    #pragma unroll
    for (int c = 0; c < 4; ++c)
      gload_lds16(A + (size_t)(m0 + arow[c]) * K + kt + aq[c] * 8, &As[(wave * 4 + c) * 512]);
    #pragma unroll
    for (int c = 0; c < CB; ++c)
      gload_lds16(W + (size_t)(n0 + brow[c]) * K + kt + bq[c] * 8, &Bs[(wave * CB + c) * 512]);
    __syncthreads();
    #pragma unroll
    for (int kc = 0; kc < 2; ++kc) {
      bf8_t af[4], bfv[MJ];
      #pragma unroll
      for (int i = 0; i < 4; ++i) {
        const int r = wm + i * 16 + am;
        af[i] = *(const bf8_t*)&As[r * 64 + (((kc * 4 + quad) ^ (r & 7)) * 8)];
      }
      #pragma unroll
      for (int j = 0; j < MJ; ++j) {
        const int r = wn + j * 16 + am;
        bfv[j] = *(const bf8_t*)&Bs[r * 64 + (((kc * 4 + quad) ^ (r & 7)) * 8)];
      }
      #pragma unroll
      for (int i = 0; i < 4; ++i)
        #pragma unroll
        for (int j = 0; j < MJ; ++j) acc[i][j] = mfma16(af[i], bfv[j], acc[i][j]);
    }
    __syncthreads();
  }

  const int cb = n0 + wn + am;
  const int rb = m0 + wm + quad * 4;
  #pragma unroll
  for (int j = 0; j < MJ; ++j) {
    const int col = cb + j * 16;
    const float bv = bias[col];
    #pragma unroll
    for (int i = 0; i < 4; ++i) {
      #pragma unroll
      for (int r = 0; r < 4; ++r) {
        const int row = rb + i * 16 + r;
        float v = acc[i][j][r] + bv;
        if constexpr (MODE == 0) {
          const int b = row >> 8, n = row & (N_ - 1);
          const int h = col >> 6, hd = col & (HD_ - 1);
          u16* dst = (u16*)(proj == 0 ? d0 : (proj == 1 ? d1 : d2));
          const size_t idx = (proj < 2) ? (((size_t)(b * H_ + h) * N_ + n) * HD_ + hd)
                                        : (((size_t)(b * H_ + h) * HD_ + hd) * N_ + n);
          dst[idx] = f2bf(v);
        } else if constexpr (MODE == 2) {
          v += ((const float*)res)[(size_t)row * D_ + col];
          ((float*)d0)[(size_t)row * D_ + col] = v;
        } else if constexpr (MODE == 3) {
          v = v / (1.f + __expf(-v));
          ((u16*)d0)[(size_t)row * 2048 + col] = f2bf(v);
        } else {
          v += ((const float*)res)[(size_t)row * D_ + col];
          v *= nmask[row];
          ((float*)d0)[(size_t)row * D_ + col] = v;
        }
      }
    }
  }
}

extern "C" void kernel_launch(void* const* d_in, const int* in_sizes, int n_in,
                              void* d_out, int out_size, void* d_ws, size_t ws_size,
                              hipStream_t stream) {
  const float* x     = (const float*)d_in[0];
  const float* nm    = (const float*)d_in[1];
  const int*   edges = (const int*)d_in[2];
  const float* rmask = (const float*)d_in[3];
  const float* remb  = (const float*)d_in[4];
  const float* rgeo  = (const float*)d_in[5];
  const float* Wq = (const float*)d_in[6];  const float* bq = (const float*)d_in[7];
  const float* Wk = (const float*)d_in[8];  const float* bk = (const float*)d_in[9];
  const float* Wv = (const float*)d_in[10]; const float* bv = (const float*)d_in[11];
  const float* Web = (const float*)d_in[12]; const float* beb = (const float*)d_in[13];
  const float* glng = (const float*)d_in[14]; const float* glnb = (const float*)d_in[15];
  const float* Wgeo = (const float*)d_in[16]; const float* bgeo = (const float*)d_in[17];
  const float* Wout = (const float*)d_in[18]; const float* bout = (const float*)d_in[19];
  const float* ng = (const float*)d_in[20]; const float* nb = (const float*)d_in[21];
  const float* fg = (const float*)d_in[22]; const float* fb = (const float*)d_in[23];
  const float* Wff1 = (const float*)d_in[24]; const float* bff1 = (const float*)d_in[25];
  const float* Wff2 = (const float*)d_in[26]; const float* bff2 = (const float*)d_in[27];

  char* ws = (char*)d_ws;
  // Workspace (peak 49,283,072 B — same as rounds 4-8):
  u16*   xn      = (u16*)(ws + 0);
  u16*   qb      = (u16*)(ws + 8388608);
  u16*   kb      = (u16*)(ws + 16777216);
  u16*   vtb     = (u16*)(ws + 25165824);
  u16*   h1      = (u16*)(ws + 0);          // overlays dead xn/qb/kb/vtb in FF
  int*   win     = (int*)(ws + 33554432);
  u16*   x2n     = (u16*)(ws + 33554432);   // overlays dead win
  float* tb      = (float*)(ws + 41943040);
  u16* Wq16   = (u16*)(ws + 42991616);
  u16* Wk16   = (u16*)(ws + 43515904);
  u16* Wv16   = (u16*)(ws + 44040192);
  u16* Wout16 = (u16*)(ws + 44564480);
  u16* Wff116 = (u16*)(ws + 45088768);
  u16* Wff216 = (u16*)(ws + 47185920);
  u16*   attnout = xn;
  float* out     = (float*)d_out;

  // 0. win init, then fused prep (cvt + ln1 + scatter + edge-bias GEMM) in ONE launch
  hipMemsetAsync(win, 0xFF, (size_t)B_ * N_ * N_ * sizeof(int), stream);
  prep_kernel<<<11904, 256, 0, stream>>>(
      Wq, Wk, Wv, Wout, Wff1, Wff2, Wq16, Wk16, Wv16, Wout16, Wff116, Wff216,
      x, ng, nb, xn,
      edges, rmask, win,
      remb, rgeo, Web, beb, glng, glnb, Wgeo, bgeo, tb);
  // 1. fused QKV projections (q,k: (b,h,n,hd) ; v: transposed (b,h,hd,n))
  gemm_k<0, 128><<<dim3(64, 12), 256, 0, stream>>>(xn, Wq16, Wk16, Wv16, bq, bk, bv,
                                                   (void*)qb, (void*)kb, (void*)vtb,
                                                   nullptr, nullptr, D_);
  // 2. attention -> attnout (bf16)
  attn_kernel<<<dim3(N_ / 64, H_, B_), 256, 0, stream>>>(qb, kb, vtb, tb, win, nm, attnout);
  // 3. x2 = x + attnout @ Wout^T + bout  -> d_out (f32)
  gemm_k<2, 64><<<dim3(64, 8), 256, 0, stream>>>(attnout, Wout16, nullptr, nullptr,
                                                 bout, nullptr, nullptr,
                                                 (void*)out, nullptr, nullptr,
                                                 (const void*)x, nullptr, D_);
  // 4. x2n = LN(x2)
  ln_kernel<<<B_ * N_, 256, 0, stream>>>(out, fg, fb, x2n);
  // 5. h1 = silu(x2n @ Wff1^T + bff1)
  gemm_k<3, 128><<<dim3(64, 16), 256, 0, stream>>>(x2n, Wff116, nullptr, nullptr,
                                                   bff1, nullptr, nullptr,
                                                   (void*)h1, nullptr, nullptr, nullptr, nullptr, D_);
  // 6. out = (x2 + h1 @ Wff2^T + bff2) * node_mask
  gemm_k<4, 64><<<dim3(64, 8), 256, 0, stream>>>(h1, Wff216, nullptr, nullptr,
                                                 bff2, nullptr, nullptr,
                                                 (void*)out, nullptr, nullptr,
                                                 (const void*)out, nm, 2048);
}